// Round 1
// baseline (6257.602 us; speedup 1.0000x reference)
//
#include <hip/hip_runtime.h>

#define T_DIM 128
#define B_DIM 256
#define H_DIM 1024
#define E_DIM 1024
#define Z_DIM 512

typedef __attribute__((ext_vector_type(8))) short short8;
typedef __attribute__((ext_vector_type(4))) float f32x4;

__device__ __forceinline__ unsigned short f2bf(float f) {
  unsigned u = __float_as_uint(f);
  u += 0x7fffu + ((u >> 16) & 1u);   // round-to-nearest-even
  return (unsigned short)(u >> 16);
}
__device__ __forceinline__ float sigf(float x) { return 1.0f / (1.0f + __expf(-x)); }
__device__ __forceinline__ float tanhf_(float x) { return 2.0f * sigf(2.0f * x) - 1.0f; }

// ---------------- prep kernels ----------------

// Recurrent weights are used as h @ W^T: B[k][n] = W[n][k] -> original row-major
// layout IS the [n][k] layout we want. Just convert f32 -> bf16.
__global__ void cvt_wr(const float* __restrict__ p0, const float* __restrict__ p1,
                       const float* __restrict__ p2, const float* __restrict__ p3,
                       unsigned short* __restrict__ out) {
  size_t i = (size_t)blockIdx.x * 256 + threadIdx.x;      // 0 .. 1M-1
  const float* in = blockIdx.y == 0 ? p0 : blockIdx.y == 1 ? p1 : blockIdx.y == 2 ? p2 : p3;
  out[(size_t)blockIdx.y * (H_DIM * H_DIM) + i] = f2bf(in[i]);
}

// Input-side weights are [K][N] used as x @ W: we need B[k][n] contiguous in k,
// i.e. out[n][k] = in[k][n]. LDS-tiled transpose, f32 in, bf16 out.
__global__ void transpose_k(const float* __restrict__ p0, const float* __restrict__ p1,
                            const float* __restrict__ p2, const float* __restrict__ p3,
                            unsigned short* __restrict__ out, int K, int N) {
  const float* in = blockIdx.z == 0 ? p0 : blockIdx.z == 1 ? p1 : blockIdx.z == 2 ? p2 : p3;
  unsigned short* o = out + (size_t)blockIdx.z * K * N;
  __shared__ float tile[32][33];
  int n0 = blockIdx.x * 32;
  int k0 = blockIdx.y * 32;
#pragma unroll
  for (int i = threadIdx.y; i < 32; i += 8)
    tile[i][threadIdx.x] = in[(size_t)(k0 + i) * N + (n0 + threadIdx.x)];
  __syncthreads();
#pragma unroll
  for (int i = threadIdx.y; i < 32; i += 8)
    o[(size_t)(n0 + i) * K + (k0 + threadIdx.x)] = f2bf(tile[threadIdx.x][i]);
}

// h0 = bf16(hidden); c = cell_state; bias packed [6][H] in plane order i,f,o,ctilde,l,zhat
__global__ void init_state(const float* __restrict__ hidden, const float* __restrict__ cell,
                           const float* __restrict__ bi, const float* __restrict__ bf,
                           const float* __restrict__ bo, const float* __restrict__ bl,
                           const float* __restrict__ bz, const float* __restrict__ bc,
                           unsigned short* __restrict__ h0, float* __restrict__ c0,
                           float* __restrict__ bias) {
  int i = blockIdx.x * 256 + threadIdx.x;
  const int BH = B_DIM * H_DIM;
  if (i < BH) { h0[i] = f2bf(hidden[i]); return; }
  int j = i - BH;
  if (j < BH) { c0[j] = cell[j]; return; }
  int k = j - BH;
  if (k < 6 * H_DIM) {
    int p = k / H_DIM, q = k - p * H_DIM;
    const float* src = p == 0 ? bi : p == 1 ? bf : p == 2 ? bo : p == 3 ? bc : p == 4 ? bl : bz;
    bias[k] = src[q];
  }
}

// ---------------- fused step kernel ----------------
// One launch per timestep. Grid (16 n-tiles, 16 m-tiles), 4 waves/block.
// Wave w computes a 16(m) x 16(n) output tile for all 6 gate planes:
//   planes 0..3 (i,f,o,ctilde): sum_k h[b,k] Wr[g][n][k]  (K=1024)
//                             + sum_e x[t,b,e] Wx[g][n][e] (K=1024)
//   planes 4..5 (l,zhat):       sum_z z[t,b,zk] Wz[p][n][zk] (K=512)
// then elementwise LSTM update, writes c (f32), h (bf16 ping-pong), out (f32).
__global__ __launch_bounds__(256) void lstm_step(
    int t, const float* __restrict__ x, const float* __restrict__ z,
    const unsigned short* __restrict__ Wr, const unsigned short* __restrict__ Wx,
    const unsigned short* __restrict__ Wz, const float* __restrict__ bias,
    const unsigned short* __restrict__ hin, unsigned short* __restrict__ hout,
    float* __restrict__ cbuf, float* __restrict__ out) {
  const int lane = threadIdx.x & 63;
  const int wv = threadIdx.x >> 6;
  const int m_base = blockIdx.y * 16;
  const int n_base = blockIdx.x * 64 + wv * 16;
  const int lr = lane & 15;  // A row / B col / D col
  const int lg = lane >> 4;  // k-group (A/B), row-group (D)
  const int n = n_base + lr;

  f32x4 acc[6];
#pragma unroll
  for (int p = 0; p < 6; ++p) {
    float bv = bias[p * H_DIM + n];
    acc[p] = (f32x4){bv, bv, bv, bv};
  }

  const unsigned short* hrow = hin + (size_t)(m_base + lr) * H_DIM + lg * 8;
  const float* xrow = x + ((size_t)t * B_DIM + m_base + lr) * E_DIM + lg * 8;
  const float* zrow = z + ((size_t)t * B_DIM + m_base + lr) * Z_DIM + lg * 8;
  const unsigned short* wrp = Wr + (size_t)n * H_DIM + lg * 8;
  const unsigned short* wxp = Wx + (size_t)n * E_DIM + lg * 8;
  const unsigned short* wzp = Wz + (size_t)n * Z_DIM + lg * 8;

  // ---- recurrent part: A = h (bf16), K = 1024 ----
#pragma unroll 2
  for (int kk = 0; kk < H_DIM; kk += 32) {
    short8 a = *(const short8*)(hrow + kk);
    short8 b0 = *(const short8*)(wrp + kk);
    short8 b1 = *(const short8*)(wrp + 1 * H_DIM * H_DIM + kk);
    short8 b2 = *(const short8*)(wrp + 2 * H_DIM * H_DIM + kk);
    short8 b3 = *(const short8*)(wrp + 3 * H_DIM * H_DIM + kk);
    acc[0] = __builtin_amdgcn_mfma_f32_16x16x32_bf16(a, b0, acc[0], 0, 0, 0);
    acc[1] = __builtin_amdgcn_mfma_f32_16x16x32_bf16(a, b1, acc[1], 0, 0, 0);
    acc[2] = __builtin_amdgcn_mfma_f32_16x16x32_bf16(a, b2, acc[2], 0, 0, 0);
    acc[3] = __builtin_amdgcn_mfma_f32_16x16x32_bf16(a, b3, acc[3], 0, 0, 0);
  }

  // ---- input part: A = x_t (f32 -> bf16 in reg), K = 1024 ----
#pragma unroll 2
  for (int kk = 0; kk < E_DIM; kk += 32) {
    f32x4 x0 = *(const f32x4*)(xrow + kk);
    f32x4 x1 = *(const f32x4*)(xrow + kk + 4);
    short8 a;
#pragma unroll
    for (int j = 0; j < 4; ++j) {
      a[j] = (short)f2bf(x0[j]);
      a[j + 4] = (short)f2bf(x1[j]);
    }
    short8 b0 = *(const short8*)(wxp + kk);
    short8 b1 = *(const short8*)(wxp + 1 * H_DIM * E_DIM + kk);
    short8 b2 = *(const short8*)(wxp + 2 * H_DIM * E_DIM + kk);
    short8 b3 = *(const short8*)(wxp + 3 * H_DIM * E_DIM + kk);
    acc[0] = __builtin_amdgcn_mfma_f32_16x16x32_bf16(a, b0, acc[0], 0, 0, 0);
    acc[1] = __builtin_amdgcn_mfma_f32_16x16x32_bf16(a, b1, acc[1], 0, 0, 0);
    acc[2] = __builtin_amdgcn_mfma_f32_16x16x32_bf16(a, b2, acc[2], 0, 0, 0);
    acc[3] = __builtin_amdgcn_mfma_f32_16x16x32_bf16(a, b3, acc[3], 0, 0, 0);
  }

  // ---- field part: A = z_t (f32 -> bf16 in reg), K = 512 ----
#pragma unroll 2
  for (int kk = 0; kk < Z_DIM; kk += 32) {
    f32x4 z0 = *(const f32x4*)(zrow + kk);
    f32x4 z1 = *(const f32x4*)(zrow + kk + 4);
    short8 a;
#pragma unroll
    for (int j = 0; j < 4; ++j) {
      a[j] = (short)f2bf(z0[j]);
      a[j + 4] = (short)f2bf(z1[j]);
    }
    short8 b4 = *(const short8*)(wzp + kk);
    short8 b5 = *(const short8*)(wzp + 1 * H_DIM * Z_DIM + kk);
    acc[4] = __builtin_amdgcn_mfma_f32_16x16x32_bf16(a, b4, acc[4], 0, 0, 0);
    acc[5] = __builtin_amdgcn_mfma_f32_16x16x32_bf16(a, b5, acc[5], 0, 0, 0);
  }

  // ---- epilogue: LSTM cell update. D[row=(lg*4+j)][col=lr] ----
#pragma unroll
  for (int j = 0; j < 4; ++j) {
    int b = m_base + lg * 4 + j;
    size_t idx = (size_t)b * H_DIM + n;
    float ig = sigf(acc[0][j]);
    float fg = sigf(acc[1][j]);
    float og = sigf(acc[2][j]);
    float ct = tanhf_(acc[3][j]);
    float lgate = sigf(acc[4][j]);
    float zh = tanhf_(acc[5][j]);
    float cn = fg * cbuf[idx] + ig * ct + lgate * zh;
    cbuf[idx] = cn;
    float hn = og * tanhf_(cn);
    hout[idx] = f2bf(hn);
    out[(size_t)t * (B_DIM * H_DIM) + idx] = hn;
  }
}

// ---------------- launch ----------------

extern "C" void kernel_launch(void* const* d_in, const int* in_sizes, int n_in,
                              void* d_out, int out_size, void* d_ws, size_t ws_size,
                              hipStream_t stream) {
  const float* x = (const float*)d_in[0];
  const float* z = (const float*)d_in[1];
  const float* hidden = (const float*)d_in[2];
  const float* cell = (const float*)d_in[3];
  const float* w_ih = (const float*)d_in[4];
  const float* w_oh = (const float*)d_in[5];
  const float* w_fh = (const float*)d_in[6];
  const float* w_ch = (const float*)d_in[7];
  const float* w_ix = (const float*)d_in[8];
  const float* w_ox = (const float*)d_in[9];
  const float* w_fx = (const float*)d_in[10];
  const float* w_cx = (const float*)d_in[11];
  const float* w_lx = (const float*)d_in[12];
  const float* w_zx = (const float*)d_in[13];
  const float* b_i = (const float*)d_in[14];
  const float* b_f = (const float*)d_in[15];
  const float* b_o = (const float*)d_in[16];
  const float* b_l = (const float*)d_in[17];
  const float* b_z = (const float*)d_in[18];
  const float* b_c = (const float*)d_in[19];

  char* ws = (char*)d_ws;
  unsigned short* Wr = (unsigned short*)(ws + 0);          //  8 MB  [4][1024][1024] bf16
  unsigned short* Wx = (unsigned short*)(ws + 8388608);    //  8 MB  [4][1024][1024] bf16
  unsigned short* Wz = (unsigned short*)(ws + 16777216);   //  2 MB  [2][1024][512]  bf16
  float* bias = (float*)(ws + 18874368);                   // 24 KB  [6][1024] f32
  unsigned short* h0 = (unsigned short*)(ws + 18898944);   // 512 KB
  unsigned short* h1 = (unsigned short*)(ws + 19423232);   // 512 KB
  float* cbuf = (float*)(ws + 19947520);                   //   1 MB
  float* out = (float*)d_out;

  // prep: weight convert/transpose + state init (runs every call; ~20 MB writes)
  cvt_wr<<<dim3(4096, 4), 256, 0, stream>>>(w_ih, w_fh, w_oh, w_ch, Wr);
  transpose_k<<<dim3(32, 32, 4), dim3(32, 8), 0, stream>>>(w_ix, w_fx, w_ox, w_cx, Wx, E_DIM, H_DIM);
  transpose_k<<<dim3(32, 16, 2), dim3(32, 8), 0, stream>>>(w_lx, w_zx, w_lx, w_zx, Wz, Z_DIM, H_DIM);
  init_state<<<2072, 256, 0, stream>>>(hidden, cell, b_i, b_f, b_o, b_l, b_z, b_c, h0, cbuf, bias);

  // sequential scan: one fused kernel per timestep, h ping-pong
  for (int t = 0; t < T_DIM; ++t) {
    const unsigned short* hin = (t & 1) ? h1 : h0;
    unsigned short* hout = (t & 1) ? h0 : h1;
    lstm_step<<<dim3(16, 16), 256, 0, stream>>>(t, x, z, Wr, Wx, Wz, bias, hin, hout, cbuf, out);
  }
}